// Round 6
// baseline (448.881 us; speedup 1.0000x reference)
//
#include <hip/hip_runtime.h>
#include <cstdint>
#include <cstddef>

typedef __bf16 bf16;
typedef __bf16 bf16x2 __attribute__((ext_vector_type(2)));
typedef __bf16 bf16x4 __attribute__((ext_vector_type(4)));
typedef __bf16 bf16x8 __attribute__((ext_vector_type(8)));
typedef float f32x4 __attribute__((ext_vector_type(4)));

#define S_LEN 2048
#define BATCH 2
#define DM 1024
#define NH 16
#define DKH 64
#define MTOT (S_LEN * BATCH)  // 4096

// async global->LDS, 16B per lane; LDS dest = wave-uniform base + lane*16
__device__ __forceinline__ void gload_lds16(const void* g, void* l) {
    __builtin_amdgcn_global_load_lds((const __attribute__((address_space(1))) uint32_t*)g,
                                     (__attribute__((address_space(3))) uint32_t*)l, 16, 0, 0);
}

__device__ __forceinline__ uint32_t pack2(float a, float b) {
    bf16x2 v; v[0] = (bf16)a; v[1] = (bf16)b;
    return __builtin_bit_cast(uint32_t, v);
}

// ---------------- fused fp32 -> bf16 convert ----------------
struct ConvArgs { const float* src[7]; bf16* dst[7]; };

__global__ __launch_bounds__(256) void convert_all(ConvArgs a) {
    int gid = blockIdx.x * 256 + threadIdx.x;
    int tid, off;
    if (gid < 3 * 524288) { tid = gid >> 19; off = gid & 524287; }
    else { int r = gid - 3 * 524288; tid = 3 + (r >> 17); off = r & 131071; }
    const float4* s4 = (const float4*)a.src[tid];
    float4 x = s4[2 * off], y = s4[2 * off + 1];
    bf16x8 v;
    v[0] = (bf16)x.x; v[1] = (bf16)x.y; v[2] = (bf16)x.z; v[3] = (bf16)x.w;
    v[4] = (bf16)y.x; v[5] = (bf16)y.y; v[6] = (bf16)y.z; v[7] = (bf16)y.w;
    *(bf16x8*)(a.dst[tid] + 8 * (size_t)off) = v;
}

// ---------------- GEMM core: C = A(M,K) @ Bt(N,K)^T + bias ----------------
// M-tile 128, BK=64 staged as TWO contiguous 32-halves (keeps global_load_lds legal and the
// m97-proven LDS read pattern) -> half the barriers per K-loop.
// MI=4: 2x2 waves, N-tile 128 (qkv).  MI=2: 4x1 waves, N-tile 64 (gemm_one, 2 blocks/CU).
// mode 1: V^T (B,H,DK,S) bf16 via swapped-operand C^T | mode 2: fp32 row-major
// mode 3: Q + rope + qscale | mode 4: K + rope
template<int MI>
__device__ __forceinline__ void gemm_core(const bf16* __restrict__ A, const bf16* __restrict__ Bt,
                                          const float* __restrict__ bias, void* __restrict__ out,
                                          int mode, const float* __restrict__ cosp,
                                          const float* __restrict__ sinp, bf16* As, bf16* Bs) {
    constexpr int TN = (MI == 4) ? 128 : 64;
    constexpr int BH = (TN == 128) ? 4096 : 2048;  // B half-tile elems
    const int K = DM;
    int t = threadIdx.x;
    int lane = t & 63, wave = t >> 6;
    int lm = lane & 15, quad = lane >> 4;
    int m0 = blockIdx.y * 128, n0 = blockIdx.x * TN;
    int wm, wn;
    if constexpr (MI == 4) { wm = (wave >> 1) * 64; wn = (wave & 1) * 64; }
    else { wm = wave * 32; wn = 0; }
    f32x4 acc[MI][4] = {};
    // granule (per half, per issue): row = t>>2, kc = (t&3)*8
    int rowg = t >> 2, kc = (t & 3) * 8;
    const bf16* agp0 = A + (size_t)(m0 + rowg) * K + kc;         // A issue0 (rows 0..63)
    const bf16* agp1 = A + (size_t)(m0 + 64 + rowg) * K + kc;    // A issue1 (rows 64..127)
    const bf16* bgp0 = Bt + (size_t)(n0 + rowg) * K + kc;
    const bf16* bgp1 = (TN == 128) ? Bt + (size_t)(n0 + 64 + rowg) * K + kc : nullptr;
    bf16* alds0 = As + wave * 512;          // issue0 dest (within half)
    bf16* alds1 = As + 2048 + wave * 512;   // issue1 dest
    bf16* blds0 = Bs + wave * 512;
    bf16* blds1 = Bs + 2048 + wave * 512;

    for (int k0 = 0; k0 < K; k0 += 64) {
#pragma unroll
        for (int h = 0; h < 2; ++h) {
            int ko = k0 + h * 32;
            gload_lds16(agp0 + ko, alds0 + h * 4096);
            gload_lds16(agp1 + ko, alds1 + h * 4096);
            gload_lds16(bgp0 + ko, blds0 + h * BH);
            if constexpr (TN == 128) gload_lds16(bgp1 + ko, blds1 + h * BH);
        }
        __syncthreads();
#pragma unroll
        for (int h = 0; h < 2; ++h) {
            bf16x8 af[MI], bfr[4];
#pragma unroll
            for (int i = 0; i < MI; ++i)
                af[i] = *(const bf16x8*)(As + h * 4096 + (wm + i * 16 + lm) * 32 + quad * 8);
#pragma unroll
            for (int j = 0; j < 4; ++j)
                bfr[j] = *(const bf16x8*)(Bs + h * BH + (wn + j * 16 + lm) * 32 + quad * 8);
            if (mode == 1) {  // C^T: D[m=d][n=token]
#pragma unroll
                for (int i = 0; i < MI; ++i)
#pragma unroll
                    for (int j = 0; j < 4; ++j)
                        acc[i][j] = __builtin_amdgcn_mfma_f32_16x16x32_bf16(bfr[j], af[i], acc[i][j], 0, 0, 0);
            } else {
#pragma unroll
                for (int i = 0; i < MI; ++i)
#pragma unroll
                    for (int j = 0; j < 4; ++j)
                        acc[i][j] = __builtin_amdgcn_mfma_f32_16x16x32_bf16(af[i], bfr[j], acc[i][j], 0, 0, 0);
            }
        }
        __syncthreads();
    }
    if (mode == 1) {
        // acc[i][j]: row(quad*4+r) = d local to j-tile, col(lm) = token local to i-tile
#pragma unroll
        for (int j = 0; j < 4; ++j) {
#pragma unroll
            for (int r = 0; r < 4; ++r) {
                int d = n0 + wn + j * 16 + quad * 4 + r;
                float bv = bias[d];
                int h = d >> 6, dk = d & 63;
#pragma unroll
                for (int i = 0; i < MI; ++i) {
                    int token = m0 + wm + i * 16 + lm;
                    int s = token >> 1, b = token & 1;
                    ((bf16*)out)[((size_t)(b * NH + h) * DKH + dk) * S_LEN + s] =
                        (bf16)(acc[i][j][r] + bv);
                }
            }
        }
        return;
    }
    // bias first (rope needs biased partner values)
#pragma unroll
    for (int j = 0; j < 4; ++j) {
        float bcol = bias[n0 + wn + j * 16 + lm];
#pragma unroll
        for (int i = 0; i < MI; ++i)
#pragma unroll
            for (int r = 0; r < 4; ++r) acc[i][j][r] += bcol;
    }
#pragma unroll
    for (int i = 0; i < MI; ++i) {
#pragma unroll
        for (int j = 0; j < 4; ++j) {
            int col = n0 + wn + j * 16 + lm;
#pragma unroll
            for (int r = 0; r < 4; ++r) {
                int row = m0 + wm + i * 16 + quad * 4 + r;
                float val = acc[i][j][r];
                if (mode == 2) {
                    ((float*)out)[(size_t)row * DM + col] = val;
                } else {  // 3/4: rope; partner dk^32 = acc[i][j^2][r] (same lane, same wave)
                    int s = row >> 1, dk = col & 63;
                    float c = cosp[s * 64 + dk], sn = sinp[s * 64 + dk];
                    float partner = acc[i][j ^ 2][r];
                    float v2 = val * c + (dk < 32 ? -partner : partner) * sn;
                    if (mode == 3) v2 *= 0.125f * 1.44269504088896f;  // 1/sqrt(DK) * log2(e)
                    ((bf16*)out)[(size_t)row * DM + col] = (bf16)v2;
                }
            }
        }
    }
}

struct QKVArgs {
    const bf16* A[3]; const bf16* W[3]; const float* bias[3];
    void* out[3]; const float* cs[3]; const float* sn[3]; int mode[3];
};

__global__ __launch_bounds__(256, 4) void gemm_qkv(QKVArgs args) {
    __shared__ __align__(16) bf16 As[8192];  // 2 halves x 128x32
    __shared__ __align__(16) bf16 Bs[8192];
    int z = blockIdx.z;
    gemm_core<4>(args.A[z], args.W[z], args.bias[z], args.out[z], args.mode[z],
                 args.cs[z], args.sn[z], As, Bs);
}

__global__ __launch_bounds__(256, 4) void gemm_one(const bf16* __restrict__ A, const bf16* __restrict__ Bt,
                                                   const float* __restrict__ bias, void* __restrict__ out) {
    __shared__ __align__(16) bf16 As[8192];  // 2 halves x 128x32
    __shared__ __align__(16) bf16 Bs[4096];  // 2 halves x 64x32
    gemm_core<2>(A, Bt, bias, out, 2, nullptr, nullptr, As, Bs);
}

// ---------------- Flash attention v5 (unchanged control) ----------------
// Fixed-max softmax; causal pairing {i, 31-i}; single K/V LDS buffer + register prefetch,
// XOR swizzle; Pb stride 37.
__global__ __launch_bounds__(256, 2) void flash_kernel(const bf16* __restrict__ qp, const bf16* __restrict__ kp,
                                                       const bf16* __restrict__ vT, bf16* __restrict__ ctx) {
    int qta = blockIdx.x;        // 0..15
    int qtb = 31 - qta;          // 16..31
    int bh = blockIdx.y;
    int b = bh >> 4, h = bh & 15;
    int t = threadIdx.x, lane = t & 63, wave = t >> 6;
    int lm = lane & 15, quad = lane >> 4;
    __shared__ __align__(16) bf16 Ks[64 * 64];
    __shared__ __align__(16) bf16 Vs[64 * 64];
    __shared__ __align__(16) uint32_t Pb[4][16 * 37];
    uint32_t* pw = &Pb[wave][0];
    const int q0[2] = {qta * 64 + wave * 16, qtb * 64 + wave * 16};

    bf16x8 aq[2][2];
#pragma unroll
    for (int u = 0; u < 2; ++u) {
        const bf16* qrow = qp + ((size_t)(q0[u] + lm) * BATCH + b) * DM + h * DKH;
        aq[u][0] = *(const bf16x8*)(qrow + quad * 8);
        aq[u][1] = *(const bf16x8*)(qrow + 32 + quad * 8);
    }
    f32x4 o[2][4] = {};
    float l_acc[2] = {0.f, 0.f};

    int r0 = t >> 3, c0 = t & 7;
    int r1 = r0 + 32;
    const bf16* kg0 = kp + ((size_t)r0 * BATCH + b) * DM + h * DKH + c0 * 8;
    const bf16* kg1 = kp + ((size_t)r1 * BATCH + b) * DM + h * DKH + c0 * 8;
    const bf16* vg0 = vT + ((size_t)(bh * DKH + r0)) * S_LEN + c0 * 8;
    const bf16* vg1 = vT + ((size_t)(bh * DKH + r1)) * S_LEN + c0 * 8;
    int lk0 = r0 * 64 + (c0 ^ (r0 & 7)) * 8;
    int lk1 = r1 * 64 + (c0 ^ (r1 & 7)) * 8;
    const size_t kstep = (size_t)64 * BATCH * DM;

    const int niter = qtb + 1;
    bf16x8 ka = *(const bf16x8*)kg0;
    bf16x8 kb2 = *(const bf16x8*)kg1;
    bf16x8 va = *(const bf16x8*)vg0;
    bf16x8 vb2 = *(const bf16x8*)vg1;
    *(bf16x8*)(Ks + lk0) = ka;
    *(bf16x8*)(Ks + lk1) = kb2;
    *(bf16x8*)(Vs + lk0) = va;
    *(bf16x8*)(Vs + lk1) = vb2;
    __syncthreads();

    for (int it = 0; it < niter; ++it) {
        int kv0 = it << 6;
        bool hn = (it + 1) < niter;
        if (hn) {
            size_t koff = (size_t)(it + 1) * kstep;
            ka  = *(const bf16x8*)(kg0 + koff);
            kb2 = *(const bf16x8*)(kg1 + koff);
            va  = *(const bf16x8*)(vg0 + (it + 1) * 64);
            vb2 = *(const bf16x8*)(vg1 + (it + 1) * 64);
        }
        bf16x8 kf[4][2];
#pragma unroll
        for (int nt = 0; nt < 4; ++nt) {
            int krow = nt * 16 + lm;
            kf[nt][0] = *(const bf16x8*)(Ks + krow * 64 + ((quad ^ (krow & 7)) * 8));
            kf[nt][1] = *(const bf16x8*)(Ks + krow * 64 + (((quad + 4) ^ (krow & 7)) * 8));
        }
#pragma unroll
        for (int u = 0; u < 2; ++u) {
            if (u == 0 && kv0 > q0[0] + 15) continue;
            const f32x4 zero = {0.f, 0.f, 0.f, 0.f};
            f32x4 sc[4];
#pragma unroll
            for (int nt = 0; nt < 4; ++nt) {
                sc[nt] = __builtin_amdgcn_mfma_f32_16x16x32_bf16(kf[nt][0], aq[u][0], zero, 0, 0, 0);
                sc[nt] = __builtin_amdgcn_mfma_f32_16x16x32_bf16(kf[nt][1], aq[u][1], sc[nt], 0, 0, 0);
            }
            if (kv0 + 63 > q0[u]) {
#pragma unroll
                for (int nt = 0; nt < 4; ++nt)
#pragma unroll
                    for (int r = 0; r < 4; ++r) {
                        int kvg = kv0 + nt * 16 + quad * 4 + r;
                        if (kvg > q0[u] + lm) sc[nt][r] = -1e30f;
                    }
            }
            float rs = 0.f;
            uint32_t pk[8];
#pragma unroll
            for (int nt = 0; nt < 4; ++nt)
#pragma unroll
                for (int rp = 0; rp < 2; ++rp) {
                    float p0 = exp2f(sc[nt][2 * rp]);
                    float p1 = exp2f(sc[nt][2 * rp + 1]);
                    rs += p0 + p1;
                    pk[nt * 2 + rp] = pack2(p0, p1);
                }
            l_acc[u] += rs;
#pragma unroll
            for (int nt = 0; nt < 4; ++nt)
#pragma unroll
                for (int rp = 0; rp < 2; ++rp)
                    pw[lm * 37 + nt * 8 + quad * 2 + rp] = pk[nt * 2 + rp];
            __builtin_amdgcn_wave_barrier();
            const uint32_t* pr = pw + lm * 37;
            bf16x8 pf0 = *(const bf16x8*)(pr + quad * 4);
            bf16x8 pf1 = *(const bf16x8*)(pr + 16 + quad * 4);
#pragma unroll
            for (int dt = 0; dt < 4; ++dt) {
                int vrow = dt * 16 + lm;
                bf16x8 vf0 = *(const bf16x8*)(Vs + vrow * 64 + ((quad ^ (vrow & 7)) * 8));
                bf16x8 vf1 = *(const bf16x8*)(Vs + vrow * 64 + (((quad + 4) ^ (vrow & 7)) * 8));
                o[u][dt] = __builtin_amdgcn_mfma_f32_16x16x32_bf16(vf0, pf0, o[u][dt], 0, 0, 0);
                o[u][dt] = __builtin_amdgcn_mfma_f32_16x16x32_bf16(vf1, pf1, o[u][dt], 0, 0, 0);
            }
            __builtin_amdgcn_wave_barrier();
        }
        __syncthreads();
        if (hn) {
            *(bf16x8*)(Ks + lk0) = ka;
            *(bf16x8*)(Ks + lk1) = kb2;
            *(bf16x8*)(Vs + lk0) = va;
            *(bf16x8*)(Vs + lk1) = vb2;
        }
        __syncthreads();
    }
#pragma unroll
    for (int u = 0; u < 2; ++u) {
        float l = l_acc[u];
        l += __shfl_xor(l, 16, 64);
        l += __shfl_xor(l, 32, 64);
        float linv = 1.f / l;
        int qg = q0[u] + lm;
        bf16* crow = ctx + ((size_t)qg * BATCH + b) * DM + h * DKH;
#pragma unroll
        for (int dt = 0; dt < 4; ++dt) {
            bf16x4 v;
#pragma unroll
            for (int r = 0; r < 4; ++r) v[r] = (bf16)(o[u][dt][r] * linv);
            *(bf16x4*)(crow + dt * 16 + quad * 4) = v;
        }
    }
}

extern "C" void kernel_launch(void* const* d_in, const int* in_sizes, int n_in,
                              void* d_out, int out_size, void* d_ws, size_t ws_size,
                              hipStream_t stream) {
    const float* Q    = (const float*)d_in[0];
    const float* K    = (const float*)d_in[1];
    const float* V    = (const float*)d_in[2];
    const float* Wq   = (const float*)d_in[3];
    const float* bq   = (const float*)d_in[4];
    const float* Wk   = (const float*)d_in[5];
    const float* bk   = (const float*)d_in[6];
    const float* Wv   = (const float*)d_in[7];
    const float* bv   = (const float*)d_in[8];
    const float* Wo   = (const float*)d_in[9];
    const float* bo   = (const float*)d_in[10];
    const float* qcos = (const float*)d_in[11];
    const float* qsin = (const float*)d_in[12];
    const float* kcos = (const float*)d_in[13];
    const float* ksin = (const float*)d_in[14];
    // d_in[15] = mask: deterministic causal triu(k=1); applied analytically.

    char* ws = (char*)d_ws;
    const size_t SZ_ACT = (size_t)MTOT * DM * sizeof(bf16);  // 8 MiB
    const size_t SZ_W   = (size_t)DM * DM * sizeof(bf16);    // 2 MiB
    bf16* qb  = (bf16*)ws; ws += SZ_ACT;
    bf16* kb  = (bf16*)ws; ws += SZ_ACT;
    bf16* vb  = (bf16*)ws; ws += SZ_ACT;
    bf16* wqb = (bf16*)ws; ws += SZ_W;
    bf16* wkb = (bf16*)ws; ws += SZ_W;
    bf16* wvb = (bf16*)ws; ws += SZ_W;
    bf16* wob = (bf16*)ws; ws += SZ_W;
    bf16* qpr = (bf16*)ws; ws += SZ_ACT;
    bf16* kpr = (bf16*)ws; ws += SZ_ACT;
    bf16* vTp = (bf16*)ws; ws += SZ_ACT;
    bf16* ctx = (bf16*)ws; ws += SZ_ACT;

    ConvArgs ca;
    ca.src[0] = Q;  ca.dst[0] = qb;
    ca.src[1] = K;  ca.dst[1] = kb;
    ca.src[2] = V;  ca.dst[2] = vb;
    ca.src[3] = Wq; ca.dst[3] = wqb;
    ca.src[4] = Wk; ca.dst[4] = wkb;
    ca.src[5] = Wv; ca.dst[5] = wvb;
    ca.src[6] = Wo; ca.dst[6] = wob;
    convert_all<<<8192, 256, 0, stream>>>(ca);

    QKVArgs qa;
    qa.A[0] = qb; qa.W[0] = wqb; qa.bias[0] = bq; qa.out[0] = qpr; qa.mode[0] = 3; qa.cs[0] = qcos; qa.sn[0] = qsin;
    qa.A[1] = kb; qa.W[1] = wkb; qa.bias[1] = bk; qa.out[1] = kpr; qa.mode[1] = 4; qa.cs[1] = kcos; qa.sn[1] = ksin;
    qa.A[2] = vb; qa.W[2] = wvb; qa.bias[2] = bv; qa.out[2] = vTp; qa.mode[2] = 1; qa.cs[2] = nullptr; qa.sn[2] = nullptr;
    gemm_qkv<<<dim3(DM / 128, MTOT / 128, 3), 256, 0, stream>>>(qa);

    flash_kernel<<<dim3(16, BATCH * NH), 256, 0, stream>>>(qpr, kpr, vTp, ctx);

    gemm_one<<<dim3(DM / 64, MTOT / 128), 256, 0, stream>>>(ctx, wob, bo, (float*)d_out);
}

// Round 7
// 270.915 us; speedup vs baseline: 1.6569x; 1.6569x over previous
//
#include <hip/hip_runtime.h>
#include <cstdint>
#include <cstddef>

typedef __bf16 bf16;
typedef __bf16 bf16x2 __attribute__((ext_vector_type(2)));
typedef __bf16 bf16x4 __attribute__((ext_vector_type(4)));
typedef __bf16 bf16x8 __attribute__((ext_vector_type(8)));
typedef float f32x4 __attribute__((ext_vector_type(4)));

#define S_LEN 2048
#define BATCH 2
#define DM 1024
#define NH 16
#define DKH 64
#define MTOT (S_LEN * BATCH)  // 4096

// async global->LDS, 16B per lane; LDS dest = wave-uniform base + lane*16
__device__ __forceinline__ void gload_lds16(const void* g, void* l) {
    __builtin_amdgcn_global_load_lds((const __attribute__((address_space(1))) uint32_t*)g,
                                     (__attribute__((address_space(3))) uint32_t*)l, 16, 0, 0);
}

__device__ __forceinline__ uint32_t pack2(float a, float b) {
    bf16x2 v; v[0] = (bf16)a; v[1] = (bf16)b;
    return __builtin_bit_cast(uint32_t, v);
}

// ---------------- fused fp32 -> bf16 convert ----------------
struct ConvArgs { const float* src[7]; bf16* dst[7]; };

__global__ __launch_bounds__(256) void convert_all(ConvArgs a) {
    int gid = blockIdx.x * 256 + threadIdx.x;
    int tid, off;
    if (gid < 3 * 524288) { tid = gid >> 19; off = gid & 524287; }
    else { int r = gid - 3 * 524288; tid = 3 + (r >> 17); off = r & 131071; }
    const float4* s4 = (const float4*)a.src[tid];
    float4 x = s4[2 * off], y = s4[2 * off + 1];
    bf16x8 v;
    v[0] = (bf16)x.x; v[1] = (bf16)x.y; v[2] = (bf16)x.z; v[3] = (bf16)x.w;
    v[4] = (bf16)y.x; v[5] = (bf16)y.y; v[6] = (bf16)y.z; v[7] = (bf16)y.w;
    *(bf16x8*)(a.dst[tid] + 8 * (size_t)off) = v;
}

// ---------------- GEMM core: C = A(M,K) @ Bt(N,K)^T + bias ----------------
// M-tile 128, BK=64 staged as TWO contiguous 32-halves (keeps global_load_lds legal and the
// m97-proven LDS read pattern) -> half the barriers per K-loop.
// MI=4: 2x2 waves, N-tile 128 (qkv).  MI=2: 4x1 waves, N-tile 64 (gemm_one, 2 blocks/CU).
// mode 1: V^T (B,H,DK,S) bf16 via swapped-operand C^T | mode 2: fp32 row-major
// mode 3: Q + rope + qscale | mode 4: K + rope
template<int MI>
__device__ __forceinline__ void gemm_core(const bf16* __restrict__ A, const bf16* __restrict__ Bt,
                                          const float* __restrict__ bias, void* __restrict__ out,
                                          int mode, const float* __restrict__ cosp,
                                          const float* __restrict__ sinp, bf16* As, bf16* Bs) {
    constexpr int TN = (MI == 4) ? 128 : 64;
    constexpr int BH = (TN == 128) ? 4096 : 2048;  // B half-tile elems
    const int K = DM;
    int t = threadIdx.x;
    int lane = t & 63, wave = t >> 6;
    int lm = lane & 15, quad = lane >> 4;
    int m0 = blockIdx.y * 128, n0 = blockIdx.x * TN;
    int wm, wn;
    if constexpr (MI == 4) { wm = (wave >> 1) * 64; wn = (wave & 1) * 64; }
    else { wm = wave * 32; wn = 0; }
    f32x4 acc[MI][4] = {};
    // granule (per half, per issue): row = t>>2, kc = (t&3)*8
    int rowg = t >> 2, kc = (t & 3) * 8;
    const bf16* agp0 = A + (size_t)(m0 + rowg) * K + kc;         // A issue0 (rows 0..63)
    const bf16* agp1 = A + (size_t)(m0 + 64 + rowg) * K + kc;    // A issue1 (rows 64..127)
    const bf16* bgp0 = Bt + (size_t)(n0 + rowg) * K + kc;
    const bf16* bgp1 = (TN == 128) ? Bt + (size_t)(n0 + 64 + rowg) * K + kc : nullptr;
    bf16* alds0 = As + wave * 512;          // issue0 dest (within half)
    bf16* alds1 = As + 2048 + wave * 512;   // issue1 dest
    bf16* blds0 = Bs + wave * 512;
    bf16* blds1 = Bs + 2048 + wave * 512;

    for (int k0 = 0; k0 < K; k0 += 64) {
#pragma unroll
        for (int h = 0; h < 2; ++h) {
            int ko = k0 + h * 32;
            gload_lds16(agp0 + ko, alds0 + h * 4096);
            gload_lds16(agp1 + ko, alds1 + h * 4096);
            gload_lds16(bgp0 + ko, blds0 + h * BH);
            if constexpr (TN == 128) gload_lds16(bgp1 + ko, blds1 + h * BH);
        }
        __syncthreads();
#pragma unroll
        for (int h = 0; h < 2; ++h) {
            bf16x8 af[MI], bfr[4];
#pragma unroll
            for (int i = 0; i < MI; ++i)
                af[i] = *(const bf16x8*)(As + h * 4096 + (wm + i * 16 + lm) * 32 + quad * 8);
#pragma unroll
            for (int j = 0; j < 4; ++j)
                bfr[j] = *(const bf16x8*)(Bs + h * BH + (wn + j * 16 + lm) * 32 + quad * 8);
            if (mode == 1) {  // C^T: D[m=d][n=token]
#pragma unroll
                for (int i = 0; i < MI; ++i)
#pragma unroll
                    for (int j = 0; j < 4; ++j)
                        acc[i][j] = __builtin_amdgcn_mfma_f32_16x16x32_bf16(bfr[j], af[i], acc[i][j], 0, 0, 0);
            } else {
#pragma unroll
                for (int i = 0; i < MI; ++i)
#pragma unroll
                    for (int j = 0; j < 4; ++j)
                        acc[i][j] = __builtin_amdgcn_mfma_f32_16x16x32_bf16(af[i], bfr[j], acc[i][j], 0, 0, 0);
            }
        }
        __syncthreads();
    }
    if (mode == 1) {
        // acc[i][j]: row(quad*4+r) = d local to j-tile, col(lm) = token local to i-tile
#pragma unroll
        for (int j = 0; j < 4; ++j) {
#pragma unroll
            for (int r = 0; r < 4; ++r) {
                int d = n0 + wn + j * 16 + quad * 4 + r;
                float bv = bias[d];
                int h = d >> 6, dk = d & 63;
#pragma unroll
                for (int i = 0; i < MI; ++i) {
                    int token = m0 + wm + i * 16 + lm;
                    int s = token >> 1, b = token & 1;
                    ((bf16*)out)[((size_t)(b * NH + h) * DKH + dk) * S_LEN + s] =
                        (bf16)(acc[i][j][r] + bv);
                }
            }
        }
        return;
    }
    // bias first (rope needs biased partner values)
#pragma unroll
    for (int j = 0; j < 4; ++j) {
        float bcol = bias[n0 + wn + j * 16 + lm];
#pragma unroll
        for (int i = 0; i < MI; ++i)
#pragma unroll
            for (int r = 0; r < 4; ++r) acc[i][j][r] += bcol;
    }
#pragma unroll
    for (int i = 0; i < MI; ++i) {
#pragma unroll
        for (int j = 0; j < 4; ++j) {
            int col = n0 + wn + j * 16 + lm;
#pragma unroll
            for (int r = 0; r < 4; ++r) {
                int row = m0 + wm + i * 16 + quad * 4 + r;
                float val = acc[i][j][r];
                if (mode == 2) {
                    ((float*)out)[(size_t)row * DM + col] = val;
                } else {  // 3/4: rope; partner dk^32 = acc[i][j^2][r] (same lane, same wave)
                    int s = row >> 1, dk = col & 63;
                    float c = cosp[s * 64 + dk], sn = sinp[s * 64 + dk];
                    float partner = acc[i][j ^ 2][r];
                    float v2 = val * c + (dk < 32 ? -partner : partner) * sn;
                    if (mode == 3) v2 *= 0.125f * 1.44269504088896f;  // 1/sqrt(DK) * log2(e)
                    ((bf16*)out)[(size_t)row * DM + col] = (bf16)v2;
                }
            }
        }
    }
}

struct QKVArgs {
    const bf16* A[3]; const bf16* W[3]; const float* bias[3];
    void* out[3]; const float* cs[3]; const float* sn[3]; int mode[3];
};

// (256,2): VGPR cap 256 — BK=64 body needs ~160; (256,4) capped at 128 and SPILLED (R6:
// WRITE_SIZE 658 MB of scratch traffic, 3.2x regression). Do not re-tighten.
__global__ __launch_bounds__(256, 2) void gemm_qkv(QKVArgs args) {
    __shared__ __align__(16) bf16 As[8192];  // 2 halves x 128x32
    __shared__ __align__(16) bf16 Bs[8192];
    int z = blockIdx.z;
    gemm_core<4>(args.A[z], args.W[z], args.bias[z], args.out[z], args.mode[z],
                 args.cs[z], args.sn[z], As, Bs);
}

__global__ __launch_bounds__(256, 2) void gemm_one(const bf16* __restrict__ A, const bf16* __restrict__ Bt,
                                                   const float* __restrict__ bias, void* __restrict__ out) {
    __shared__ __align__(16) bf16 As[8192];  // 2 halves x 128x32
    __shared__ __align__(16) bf16 Bs[4096];  // 2 halves x 64x32
    gemm_core<2>(A, Bt, bias, out, 2, nullptr, nullptr, As, Bs);
}

// ---------------- Flash attention v5 (unchanged control) ----------------
// Fixed-max softmax; causal pairing {i, 31-i}; single K/V LDS buffer + register prefetch,
// XOR swizzle; Pb stride 37.
__global__ __launch_bounds__(256, 2) void flash_kernel(const bf16* __restrict__ qp, const bf16* __restrict__ kp,
                                                       const bf16* __restrict__ vT, bf16* __restrict__ ctx) {
    int qta = blockIdx.x;        // 0..15
    int qtb = 31 - qta;          // 16..31
    int bh = blockIdx.y;
    int b = bh >> 4, h = bh & 15;
    int t = threadIdx.x, lane = t & 63, wave = t >> 6;
    int lm = lane & 15, quad = lane >> 4;
    __shared__ __align__(16) bf16 Ks[64 * 64];
    __shared__ __align__(16) bf16 Vs[64 * 64];
    __shared__ __align__(16) uint32_t Pb[4][16 * 37];
    uint32_t* pw = &Pb[wave][0];
    const int q0[2] = {qta * 64 + wave * 16, qtb * 64 + wave * 16};

    bf16x8 aq[2][2];
#pragma unroll
    for (int u = 0; u < 2; ++u) {
        const bf16* qrow = qp + ((size_t)(q0[u] + lm) * BATCH + b) * DM + h * DKH;
        aq[u][0] = *(const bf16x8*)(qrow + quad * 8);
        aq[u][1] = *(const bf16x8*)(qrow + 32 + quad * 8);
    }
    f32x4 o[2][4] = {};
    float l_acc[2] = {0.f, 0.f};

    int r0 = t >> 3, c0 = t & 7;
    int r1 = r0 + 32;
    const bf16* kg0 = kp + ((size_t)r0 * BATCH + b) * DM + h * DKH + c0 * 8;
    const bf16* kg1 = kp + ((size_t)r1 * BATCH + b) * DM + h * DKH + c0 * 8;
    const bf16* vg0 = vT + ((size_t)(bh * DKH + r0)) * S_LEN + c0 * 8;
    const bf16* vg1 = vT + ((size_t)(bh * DKH + r1)) * S_LEN + c0 * 8;
    int lk0 = r0 * 64 + (c0 ^ (r0 & 7)) * 8;
    int lk1 = r1 * 64 + (c0 ^ (r1 & 7)) * 8;
    const size_t kstep = (size_t)64 * BATCH * DM;

    const int niter = qtb + 1;
    bf16x8 ka = *(const bf16x8*)kg0;
    bf16x8 kb2 = *(const bf16x8*)kg1;
    bf16x8 va = *(const bf16x8*)vg0;
    bf16x8 vb2 = *(const bf16x8*)vg1;
    *(bf16x8*)(Ks + lk0) = ka;
    *(bf16x8*)(Ks + lk1) = kb2;
    *(bf16x8*)(Vs + lk0) = va;
    *(bf16x8*)(Vs + lk1) = vb2;
    __syncthreads();

    for (int it = 0; it < niter; ++it) {
        int kv0 = it << 6;
        bool hn = (it + 1) < niter;
        if (hn) {
            size_t koff = (size_t)(it + 1) * kstep;
            ka  = *(const bf16x8*)(kg0 + koff);
            kb2 = *(const bf16x8*)(kg1 + koff);
            va  = *(const bf16x8*)(vg0 + (it + 1) * 64);
            vb2 = *(const bf16x8*)(vg1 + (it + 1) * 64);
        }
        bf16x8 kf[4][2];
#pragma unroll
        for (int nt = 0; nt < 4; ++nt) {
            int krow = nt * 16 + lm;
            kf[nt][0] = *(const bf16x8*)(Ks + krow * 64 + ((quad ^ (krow & 7)) * 8));
            kf[nt][1] = *(const bf16x8*)(Ks + krow * 64 + (((quad + 4) ^ (krow & 7)) * 8));
        }
#pragma unroll
        for (int u = 0; u < 2; ++u) {
            if (u == 0 && kv0 > q0[0] + 15) continue;
            const f32x4 zero = {0.f, 0.f, 0.f, 0.f};
            f32x4 sc[4];
#pragma unroll
            for (int nt = 0; nt < 4; ++nt) {
                sc[nt] = __builtin_amdgcn_mfma_f32_16x16x32_bf16(kf[nt][0], aq[u][0], zero, 0, 0, 0);
                sc[nt] = __builtin_amdgcn_mfma_f32_16x16x32_bf16(kf[nt][1], aq[u][1], sc[nt], 0, 0, 0);
            }
            if (kv0 + 63 > q0[u]) {
#pragma unroll
                for (int nt = 0; nt < 4; ++nt)
#pragma unroll
                    for (int r = 0; r < 4; ++r) {
                        int kvg = kv0 + nt * 16 + quad * 4 + r;
                        if (kvg > q0[u] + lm) sc[nt][r] = -1e30f;
                    }
            }
            float rs = 0.f;
            uint32_t pk[8];
#pragma unroll
            for (int nt = 0; nt < 4; ++nt)
#pragma unroll
                for (int rp = 0; rp < 2; ++rp) {
                    float p0 = exp2f(sc[nt][2 * rp]);
                    float p1 = exp2f(sc[nt][2 * rp + 1]);
                    rs += p0 + p1;
                    pk[nt * 2 + rp] = pack2(p0, p1);
                }
            l_acc[u] += rs;
#pragma unroll
            for (int nt = 0; nt < 4; ++nt)
#pragma unroll
                for (int rp = 0; rp < 2; ++rp)
                    pw[lm * 37 + nt * 8 + quad * 2 + rp] = pk[nt * 2 + rp];
            __builtin_amdgcn_wave_barrier();
            const uint32_t* pr = pw + lm * 37;
            bf16x8 pf0 = *(const bf16x8*)(pr + quad * 4);
            bf16x8 pf1 = *(const bf16x8*)(pr + 16 + quad * 4);
#pragma unroll
            for (int dt = 0; dt < 4; ++dt) {
                int vrow = dt * 16 + lm;
                bf16x8 vf0 = *(const bf16x8*)(Vs + vrow * 64 + ((quad ^ (vrow & 7)) * 8));
                bf16x8 vf1 = *(const bf16x8*)(Vs + vrow * 64 + (((quad + 4) ^ (vrow & 7)) * 8));
                o[u][dt] = __builtin_amdgcn_mfma_f32_16x16x32_bf16(vf0, pf0, o[u][dt], 0, 0, 0);
                o[u][dt] = __builtin_amdgcn_mfma_f32_16x16x32_bf16(vf1, pf1, o[u][dt], 0, 0, 0);
            }
            __builtin_amdgcn_wave_barrier();
        }
        __syncthreads();
        if (hn) {
            *(bf16x8*)(Ks + lk0) = ka;
            *(bf16x8*)(Ks + lk1) = kb2;
            *(bf16x8*)(Vs + lk0) = va;
            *(bf16x8*)(Vs + lk1) = vb2;
        }
        __syncthreads();
    }
#pragma unroll
    for (int u = 0; u < 2; ++u) {
        float l = l_acc[u];
        l += __shfl_xor(l, 16, 64);
        l += __shfl_xor(l, 32, 64);
        float linv = 1.f / l;
        int qg = q0[u] + lm;
        bf16* crow = ctx + ((size_t)qg * BATCH + b) * DM + h * DKH;
#pragma unroll
        for (int dt = 0; dt < 4; ++dt) {
            bf16x4 v;
#pragma unroll
            for (int r = 0; r < 4; ++r) v[r] = (bf16)(o[u][dt][r] * linv);
            *(bf16x4*)(crow + dt * 16 + quad * 4) = v;
        }
    }
}

extern "C" void kernel_launch(void* const* d_in, const int* in_sizes, int n_in,
                              void* d_out, int out_size, void* d_ws, size_t ws_size,
                              hipStream_t stream) {
    const float* Q    = (const float*)d_in[0];
    const float* K    = (const float*)d_in[1];
    const float* V    = (const float*)d_in[2];
    const float* Wq   = (const float*)d_in[3];
    const float* bq   = (const float*)d_in[4];
    const float* Wk   = (const float*)d_in[5];
    const float* bk   = (const float*)d_in[6];
    const float* Wv   = (const float*)d_in[7];
    const float* bv   = (const float*)d_in[8];
    const float* Wo   = (const float*)d_in[9];
    const float* bo   = (const float*)d_in[10];
    const float* qcos = (const float*)d_in[11];
    const float* qsin = (const float*)d_in[12];
    const float* kcos = (const float*)d_in[13];
    const float* ksin = (const float*)d_in[14];
    // d_in[15] = mask: deterministic causal triu(k=1); applied analytically.

    char* ws = (char*)d_ws;
    const size_t SZ_ACT = (size_t)MTOT * DM * sizeof(bf16);  // 8 MiB
    const size_t SZ_W   = (size_t)DM * DM * sizeof(bf16);    // 2 MiB
    bf16* qb  = (bf16*)ws; ws += SZ_ACT;
    bf16* kb  = (bf16*)ws; ws += SZ_ACT;
    bf16* vb  = (bf16*)ws; ws += SZ_ACT;
    bf16* wqb = (bf16*)ws; ws += SZ_W;
    bf16* wkb = (bf16*)ws; ws += SZ_W;
    bf16* wvb = (bf16*)ws; ws += SZ_W;
    bf16* wob = (bf16*)ws; ws += SZ_W;
    bf16* qpr = (bf16*)ws; ws += SZ_ACT;
    bf16* kpr = (bf16*)ws; ws += SZ_ACT;
    bf16* vTp = (bf16*)ws; ws += SZ_ACT;
    bf16* ctx = (bf16*)ws; ws += SZ_ACT;

    ConvArgs ca;
    ca.src[0] = Q;  ca.dst[0] = qb;
    ca.src[1] = K;  ca.dst[1] = kb;
    ca.src[2] = V;  ca.dst[2] = vb;
    ca.src[3] = Wq; ca.dst[3] = wqb;
    ca.src[4] = Wk; ca.dst[4] = wkb;
    ca.src[5] = Wv; ca.dst[5] = wvb;
    ca.src[6] = Wo; ca.dst[6] = wob;
    convert_all<<<8192, 256, 0, stream>>>(ca);

    QKVArgs qa;
    qa.A[0] = qb; qa.W[0] = wqb; qa.bias[0] = bq; qa.out[0] = qpr; qa.mode[0] = 3; qa.cs[0] = qcos; qa.sn[0] = qsin;
    qa.A[1] = kb; qa.W[1] = wkb; qa.bias[1] = bk; qa.out[1] = kpr; qa.mode[1] = 4; qa.cs[1] = kcos; qa.sn[1] = ksin;
    qa.A[2] = vb; qa.W[2] = wvb; qa.bias[2] = bv; qa.out[2] = vTp; qa.mode[2] = 1; qa.cs[2] = nullptr; qa.sn[2] = nullptr;
    gemm_qkv<<<dim3(DM / 128, MTOT / 128, 3), 256, 0, stream>>>(qa);

    flash_kernel<<<dim3(16, BATCH * NH), 256, 0, stream>>>(qpr, kpr, vTp, ctx);

    gemm_one<<<dim3(DM / 64, MTOT / 128), 256, 0, stream>>>(ctx, wob, bo, (float*)d_out);
}